// Round 12
// baseline (35.447 us; speedup 1.0000x reference)
//
#include <hip/hip_runtime.h>
#include <math.h>

#define KEXP 7
#define DDIM 1024
#define RDIM 128
#define TSEQ 2048
#define BBATCH 4
#define TAU_C 1.2f
#define EPS_C 1e-9f
#define LN_EPS_C 1e-5f

// ws float offsets
#define WS_S     0                    // s[b][k][1024]      : 28672 floats
#define WS_PSTAT 28672                // pstat[b][k][16][2] : 896

__device__ __forceinline__ float dot4(float4 a, float4 b) {
    return fmaf(a.x, b.x, fmaf(a.y, b.y, fmaf(a.z, b.z, a.w * b.w)));
}

// serial leftover-weight computation from softmaxed gate probs g[0..6] (one thread)
__device__ __forceinline__ void leftover_from_probs(const float* g, float* wout) {
    int i1 = 0;
    for (int j = 1; j < KEXP; ++j) if (g[j] > g[i1]) i1 = j;
    int i2 = -1;
    for (int j = 0; j < KEXP; ++j)
        if (j != i1 && (i2 < 0 || g[j] > g[i2])) i2 = j;
    int i3 = -1;
    for (int j = 0; j < KEXP; ++j)
        if (j != i1 && j != i2 && (i3 < 0 || g[j] > g[i3])) i3 = j;
    int i4 = -1;
    for (int j = 0; j < KEXP; ++j)
        if (j != i1 && j != i2 && j != i3 && (i4 < 0 || g[j] > g[i4])) i4 = j;
    float s = fmaxf(g[i3] + g[i4], EPS_C);
    float p[KEXP];
#pragma unroll
    for (int j = 0; j < KEXP; ++j) p[j] = 0.f;
    p[i3] = g[i3] / s;
    p[i4] = g[i4] / s;
    float l[KEXP], m = -1e30f;
#pragma unroll
    for (int j = 0; j < KEXP; ++j) {
        l[j] = logf(fmaxf(p[j], EPS_C)) * (1.f / TAU_C);
        m = fmaxf(m, l[j]);
    }
    float es = 0.f, w[KEXP];
#pragma unroll
    for (int j = 0; j < KEXP; ++j) { w[j] = expf(l[j] - m); es += w[j]; }
    const float inv = 1.f / es;
    float wsum = 0.f;
#pragma unroll
    for (int j = 0; j < KEXP; ++j) { w[j] *= inv; wsum += w[j]; wout[j] = w[j]; }
    wout[7] = wsum;
}

// one 16-row gate chunk (R3-proven): 4 rows/wave serial, gw register-staged.
__device__ __forceinline__ void gate_chunk(int c, const float* __restrict__ h,
                                           const float* __restrict__ gate_w,
                                           const float* __restrict__ gate_b,
                                           float* __restrict__ G,
                                           int lane, int wv) {
    const float4* gw4 = (const float4*)gate_w;
    float4 gw[KEXP][4];
#pragma unroll
    for (int k = 0; k < KEXP; ++k)
#pragma unroll
        for (int j = 0; j < 4; ++j)
            gw[k][j] = gw4[k * 256 + j * 64 + lane];
    float gb[KEXP];
#pragma unroll
    for (int k = 0; k < KEXP; ++k) gb[k] = gate_b[k];

    const int row0 = c * 16 + wv * 4;
#pragma unroll
    for (int r = 0; r < 4; ++r) {
        const int row = row0 + r;
        const float4* h4 = (const float4*)(h + (size_t)row * DDIM);
        float acc[KEXP];
#pragma unroll
        for (int k = 0; k < KEXP; ++k) acc[k] = 0.f;
#pragma unroll
        for (int j = 0; j < 4; ++j) {
            float4 hv = h4[j * 64 + lane];
#pragma unroll
            for (int k = 0; k < KEXP; ++k) {
                acc[k] = fmaf(hv.x, gw[k][j].x, acc[k]);
                acc[k] = fmaf(hv.y, gw[k][j].y, acc[k]);
                acc[k] = fmaf(hv.z, gw[k][j].z, acc[k]);
                acc[k] = fmaf(hv.w, gw[k][j].w, acc[k]);
            }
        }
#pragma unroll
        for (int k = 0; k < KEXP; ++k) {
#pragma unroll
            for (int off = 32; off > 0; off >>= 1)
                acc[k] += __shfl_xor(acc[k], off, 64);
        }
        float m = -1e30f;
#pragma unroll
        for (int k = 0; k < KEXP; ++k) { acc[k] += gb[k]; m = fmaxf(m, acc[k]); }
        float e[KEXP];
        float s = 0.f;
#pragma unroll
        for (int k = 0; k < KEXP; ++k) { e[k] = expf(acc[k] - m); s += e[k]; }
        const float inv = 1.f / s;
        if (lane == 0) {
#pragma unroll
            for (int k = 0; k < KEXP; ++k) G[row * KEXP + k] = e[k] * inv;
        }
    }
}

// ====== kernel A: sv with self-contained basis recompute. 112 blocks. ======
// block = (k, 64-d chunk). Writes s[b][k][chunk] + partial LN stats.
__global__ __launch_bounds__(256) void k_sv2(const float* __restrict__ h,
                                             const float* __restrict__ U_w,
                                             const float* __restrict__ V,
                                             float* __restrict__ ws) {
    const int k = blockIdx.x >> 4;
    const int chunk = blockIdx.x & 15;
    const int tid = threadIdx.x;
    const int lane = tid & 63;
    const int wv = tid >> 6;

    __shared__ float basis_sh[BBATCH * RDIM];    // [b*128 + r]
    __shared__ float4 part[16 * BBATCH * 16];    // [(rc*4+b)*16+col]

    // ---- phase 1: basis[b][r] = h_last[b] . U_w[r]; wave wv owns 32 r's.
    {
        float4 hf[BBATCH][4];
#pragma unroll
        for (int b = 0; b < BBATCH; ++b) {
            const float4* h4 = (const float4*)(h + ((size_t)b * TSEQ + (TSEQ - 1)) * DDIM);
#pragma unroll
            for (int j = 0; j < 4; ++j) hf[b][j] = h4[j * 64 + lane];
        }
        const int rbase = wv * 32;
        for (int rr0 = 0; rr0 < 32; rr0 += 2) {
            float4 u0[4], u1[4];
            const float4* ua = (const float4*)(U_w + (size_t)(rbase + rr0) * DDIM);
            const float4* ub = (const float4*)(U_w + (size_t)(rbase + rr0 + 1) * DDIM);
#pragma unroll
            for (int j = 0; j < 4; ++j) { u0[j] = ua[j * 64 + lane]; u1[j] = ub[j * 64 + lane]; }
            float p0[BBATCH], p1[BBATCH];
#pragma unroll
            for (int b = 0; b < BBATCH; ++b) { p0[b] = 0.f; p1[b] = 0.f; }
#pragma unroll
            for (int j = 0; j < 4; ++j) {
#pragma unroll
                for (int b = 0; b < BBATCH; ++b) {
                    p0[b] += dot4(hf[b][j], u0[j]);
                    p1[b] += dot4(hf[b][j], u1[j]);
                }
            }
#pragma unroll
            for (int off = 32; off > 0; off >>= 1) {
#pragma unroll
                for (int b = 0; b < BBATCH; ++b) {
                    p0[b] += __shfl_xor(p0[b], off, 64);
                    p1[b] += __shfl_xor(p1[b], off, 64);
                }
            }
            if (lane == 0) {
#pragma unroll
                for (int b = 0; b < BBATCH; ++b) {
                    basis_sh[b * RDIM + rbase + rr0] = p0[b];
                    basis_sh[b * RDIM + rbase + rr0 + 1] = p1[b];
                }
            }
        }
    }
    __syncthreads();

    // ---- phase 2: s_d partials over r, combine, write s + pstat.
    {
        const int col = tid & 15;
        const int rc = tid >> 4;
        const float4* V4 = (const float4*)(V + (size_t)k * RDIM * DDIM);
        float4 acc[BBATCH];
#pragma unroll
        for (int b = 0; b < BBATCH; ++b) acc[b] = make_float4(0.f, 0.f, 0.f, 0.f);
#pragma unroll
        for (int rr = 0; rr < 8; ++rr) {
            const int r = rc * 8 + rr;
            float4 v = V4[(size_t)r * 256 + chunk * 16 + col];
#pragma unroll
            for (int b = 0; b < BBATCH; ++b) {
                const float br = basis_sh[b * RDIM + r];
                acc[b].x = fmaf(br, v.x, acc[b].x);
                acc[b].y = fmaf(br, v.y, acc[b].y);
                acc[b].z = fmaf(br, v.z, acc[b].z);
                acc[b].w = fmaf(br, v.w, acc[b].w);
            }
        }
#pragma unroll
        for (int b = 0; b < BBATCH; ++b) part[(rc * 4 + b) * 16 + col] = acc[b];
    }
    __syncthreads();

    if (tid < 64) {
        const int b = tid >> 4;
        const int c = tid & 15;
        float4 s4 = make_float4(0.f, 0.f, 0.f, 0.f);
#pragma unroll
        for (int q = 0; q < 16; ++q) {
            float4 p = part[(q * 4 + b) * 16 + c];
            s4.x += p.x; s4.y += p.y; s4.z += p.z; s4.w += p.w;
        }
        ((float4*)(ws + WS_S))[(size_t)(b * KEXP + k) * 256 + chunk * 16 + c] = s4;
        float p1 = s4.x + s4.y + s4.z + s4.w;
        float p2 = dot4(s4, s4);
#pragma unroll
        for (int off = 8; off > 0; off >>= 1) {
            p1 += __shfl_xor(p1, off, 64);
            p2 += __shfl_xor(p2, off, 64);
        }
        if (c == 0) {
            ws[WS_PSTAT + ((b * KEXP + k) * 16 + chunk) * 2 + 0] = p1;
            ws[WS_PSTAT + ((b * KEXP + k) * 16 + chunk) * 2 + 1] = p2;
        }
    }
}

// ====== kernel B: gate (512 blocks) + comp w/ in-block weights (256). ======
__global__ __launch_bounds__(256) void k_gc(const float* __restrict__ h,
                                            const float* __restrict__ gate_w,
                                            const float* __restrict__ gate_b,
                                            const float* __restrict__ ws,
                                            const float* __restrict__ ln_g,
                                            const float* __restrict__ ln_b,
                                            const float* __restrict__ comp_w,
                                            const float* __restrict__ comp_b,
                                            float* __restrict__ G,
                                            float* __restrict__ out) {
    const int bid = blockIdx.x;
    const int tid = threadIdx.x;
    const int lane = tid & 63;
    const int wv = tid >> 6;

    __shared__ float sA[64];
    __shared__ float wsh[BBATCH][8];
    __shared__ float4 sB[BBATCH * 256];

    if (bid < 512) {
        gate_chunk(bid, h, gate_w, gate_b, G, lane, wv);
        return;
    }

    // ---------- comp block: weights per wave (b = wv) ----------
    {
        const int b = wv;
        const float4* h4 = (const float4*)(h + ((size_t)b * TSEQ + (TSEQ - 1)) * DDIM);
        const float4* gw4 = (const float4*)gate_w;
        float acc[KEXP];
#pragma unroll
        for (int k = 0; k < KEXP; ++k) acc[k] = 0.f;
#pragma unroll
        for (int j = 0; j < 4; ++j) {
            float4 hv = h4[j * 64 + lane];
#pragma unroll
            for (int k = 0; k < KEXP; ++k)
                acc[k] += dot4(hv, gw4[k * 256 + j * 64 + lane]);
        }
#pragma unroll
        for (int k = 0; k < KEXP; ++k) {
#pragma unroll
            for (int off = 32; off > 0; off >>= 1)
                acc[k] += __shfl_xor(acc[k], off, 64);
        }
        if (lane == 0) {
            float g[KEXP], m = -1e30f;
#pragma unroll
            for (int k = 0; k < KEXP; ++k) { g[k] = acc[k] + gate_b[k]; m = fmaxf(m, g[k]); }
            float es = 0.f;
#pragma unroll
            for (int k = 0; k < KEXP; ++k) { g[k] = expf(g[k] - m); es += g[k]; }
            const float inv = 1.f / es;
#pragma unroll
            for (int k = 0; k < KEXP; ++k) g[k] *= inv;
            leftover_from_probs(g, &wsh[b][0]);
        }
    }
    __syncthreads();

    // ---------- stats finalize: alpha, C_b, wsum ----------
    if (tid < BBATCH * KEXP) {
        const int b = tid / KEXP;
        const int k = tid % KEXP;
        float s1 = 0.f, s2 = 0.f;
#pragma unroll
        for (int c = 0; c < 16; ++c) {
            s1 += ws[WS_PSTAT + ((b * KEXP + k) * 16 + c) * 2 + 0];
            s2 += ws[WS_PSTAT + ((b * KEXP + k) * 16 + c) * 2 + 1];
        }
        const float mu = s1 * (1.f / (float)DDIM);
        const float var = s2 * (1.f / (float)DDIM) - mu * mu;
        const float rs = rsqrtf(var + LN_EPS_C);
        const float w = wsh[b][k];
        sA[b * KEXP + k] = w * rs;            // alpha
        sA[28 + b * KEXP + k] = w * rs * mu;  // alpha*mu
    }
    __syncthreads();
    if (tid < BBATCH) {
        float c = 0.f;
#pragma unroll
        for (int k = 0; k < KEXP; ++k) c += sA[28 + tid * KEXP + k];
        sA[56 + tid] = c;                      // Cb
        sA[60 + tid] = wsh[tid][7];            // wsum
    }
    __syncthreads();

    // ---------- bvec build in LDS ----------
    {
        const float4 g4 = ((const float4*)ln_g)[tid];
        const float4 b4 = ((const float4*)ln_b)[tid];
        const float4* s4p = (const float4*)(ws + WS_S);
#pragma unroll
        for (int b = 0; b < BBATCH; ++b) {
            float4 s = make_float4(0.f, 0.f, 0.f, 0.f);
#pragma unroll
            for (int k = 0; k < KEXP; ++k) {
                const float a = sA[b * KEXP + k];
                float4 v = s4p[(size_t)(b * KEXP + k) * 256 + tid];
                s.x = fmaf(a, v.x, s.x);
                s.y = fmaf(a, v.y, s.y);
                s.z = fmaf(a, v.z, s.z);
                s.w = fmaf(a, v.w, s.w);
            }
            const float C = sA[56 + b], wsum = sA[60 + b];
            float4 o;
            o.x = g4.x * (s.x - C) + b4.x * wsum;
            o.y = g4.y * (s.y - C) + b4.y * wsum;
            o.z = g4.z * (s.z - C) + b4.z * wsum;
            o.w = g4.w * (s.w - C) + b4.w * wsum;
            sB[b * 256 + tid] = o;
        }
    }
    __syncthreads();

    // ---------- comp matvec: e = (bid-512)*4 + wv ----------
    const int e = (bid - 512) * 4 + wv;
    const float4* cw4 = (const float4*)(comp_w + (size_t)e * DDIM);
    float acc[BBATCH] = {0.f, 0.f, 0.f, 0.f};
#pragma unroll
    for (int j = 0; j < 4; ++j) {
        float4 c = cw4[j * 64 + lane];
#pragma unroll
        for (int b = 0; b < BBATCH; ++b) acc[b] += dot4(c, sB[b * 256 + j * 64 + lane]);
    }
#pragma unroll
    for (int b = 0; b < BBATCH; ++b)
#pragma unroll
        for (int off = 32; off > 0; off >>= 1)
            acc[b] += __shfl_xor(acc[b], off, 64);
    if (lane == 0) {
        const float cb = comp_b[e];
#pragma unroll
        for (int b = 0; b < BBATCH; ++b)
            out[b * DDIM + e] = acc[b] + cb;
    }
}

extern "C" void kernel_launch(void* const* d_in, const int* in_sizes, int n_in,
                              void* d_out, int out_size, void* d_ws, size_t ws_size,
                              hipStream_t stream) {
    const float* h      = (const float*)d_in[0];
    const float* gate_w = (const float*)d_in[1];
    const float* gate_b = (const float*)d_in[2];
    const float* U_w    = (const float*)d_in[3];
    const float* V      = (const float*)d_in[4];
    const float* ln_g   = (const float*)d_in[5];
    const float* ln_b   = (const float*)d_in[6];
    const float* comp_w = (const float*)d_in[7];
    const float* comp_b = (const float*)d_in[8];

    float* out = (float*)d_out;                 // b: 4*1024 floats
    float* G   = out + BBATCH * DDIM;           // G: 4*2048*7 floats
    float* ws  = (float*)d_ws;

    k_sv2<<<KEXP * 16, 256, 0, stream>>>(h, U_w, V, ws);
    k_gc<<<768, 256, 0, stream>>>(h, gate_w, gate_b, ws, ln_g, ln_b,
                                  comp_w, comp_b, G, out);
}